// Round 9
// baseline (2855.951 us; speedup 1.0000x reference)
//
#include <hip/hip_runtime.h>

#define NCH 256
#define NGRAPH 512
#define HID 16
#define ROUNDS 8
#define GSLOTS 64          // graphs finalized per round
#define NPART 8            // blocks cooperating per graph

typedef __attribute__((ext_vector_type(4))) float f32x4;

__device__ __forceinline__ f32x4 ldrow(const float* __restrict__ x, int r, size_t coff) {
    return *reinterpret_cast<const f32x4*>(x + (size_t)r * NCH + coff);
}

__device__ __forceinline__ void write_seg(const float* __restrict__ x,
                                          float* __restrict__ out,
                                          const float* __restrict__ scale,
                                          int* __restrict__ flg,
                                          int pg, int pplo, int pphi,
                                          int tid, int rg, int c4, size_t coff)
{
    if (tid == 0) {
        while (__hip_atomic_load(&flg[pg], __ATOMIC_ACQUIRE, __HIP_MEMORY_SCOPE_AGENT) == 0)
            __builtin_amdgcn_s_sleep(16);
    }
    __syncthreads();
    const f32x4 scv = *reinterpret_cast<const f32x4*>(scale + (size_t)pg * NCH + c4 * 4);
    int r = pplo + rg;
    for (; r + 24 < pphi; r += 32) {
        f32x4 v0 = ldrow(x, r     , coff);
        f32x4 v1 = ldrow(x, r +  8, coff);
        f32x4 v2 = ldrow(x, r + 16, coff);
        f32x4 v3 = ldrow(x, r + 24, coff);
        __builtin_nontemporal_store(v0 * scv, reinterpret_cast<f32x4*>(out + (size_t)(r     ) * NCH + coff));
        __builtin_nontemporal_store(v1 * scv, reinterpret_cast<f32x4*>(out + (size_t)(r +  8) * NCH + coff));
        __builtin_nontemporal_store(v2 * scv, reinterpret_cast<f32x4*>(out + (size_t)(r + 16) * NCH + coff));
        __builtin_nontemporal_store(v3 * scv, reinterpret_cast<f32x4*>(out + (size_t)(r + 24) * NCH + coff));
    }
    for (; r < pphi; r += 8) {
        __builtin_nontemporal_store(ldrow(x, r, coff) * scv,
                                    reinterpret_cast<f32x4*>(out + (size_t)r * NCH + coff));
    }
}

// Depth-8 producer/consumer pipeline, full chip width every round.
// Round k: all 512 blocks pool partials of graphs [k*64, k*64+64) (8 blocks
// per graph); 8th arriver reduces+MLP+publishes scale; each block then writes
// (NT) the rows it pooled in round k-1 (L3-resident). Reads and writes are
// concurrent for rounds 1..7; pure-read head and write tail are 64 MB each.
__global__ __launch_bounds__(512, 4) void graph_se_pipe(
    const float* __restrict__ x,
    const int* __restrict__ batch,
    const float* __restrict__ W1,
    const float* __restrict__ W2,
    float* __restrict__ out,
    float* __restrict__ part,    // [2][GSLOTS][NPART][NCH] (round-parity dbuf)
    float* __restrict__ scale,   // [NGRAPH][NCH]
    int* __restrict__ cnt,       // [NGRAPH], zeroed per launch
    int* __restrict__ flg,       // [NGRAPH], zeroed per launch
    int n)
{
    const int b   = blockIdx.x;
    const int tid = threadIdx.x;
    const int j     = b & (NPART - 1);   // partial index within graph
    const int gslot = b >> 3;            // graph slot 0..63
    const int rg = tid >> 6;             // wave 0..7
    const int c4 = tid & 63;
    const size_t coff = (size_t)c4 * 4;

    __shared__ int   s_bnd[2];
    __shared__ int   s_io;
    __shared__ float s_part[NPART][NCH];
    __shared__ float s_vec[NCH];
    __shared__ float s_hp[HID][17];
    __shared__ float s_h[HID];

    int pg = 0, pplo = 0, pphi = 0;

    for (int k = 0; k < ROUNDS; ++k) {
        const int g = k * GSLOTS + gslot;
        if (tid < 2) {
            int v = g + tid;
            int lo = 0, hi = n;
            while (lo < hi) { int mid = (lo + hi) >> 1; if (batch[mid] < v) lo = mid + 1; else hi = mid; }
            s_bnd[tid] = lo;
        }
        __syncthreads();
        const int lo  = s_bnd[0], hi = s_bnd[1];
        const int len = hi - lo;
        const int plo = lo + (int)(((long long)len * j) >> 3);
        const int phi = lo + (int)(((long long)len * (j + 1)) >> 3);

        // ---- pool partial rows [plo, phi), 8 waves, 4 loads in flight ----
        f32x4 acc = (f32x4)(0.f);
        int r = plo + rg;
        for (; r + 24 < phi; r += 32) {
            f32x4 v0 = ldrow(x, r     , coff);
            f32x4 v1 = ldrow(x, r +  8, coff);
            f32x4 v2 = ldrow(x, r + 16, coff);
            f32x4 v3 = ldrow(x, r + 24, coff);
            acc += (v0 + v1) + (v2 + v3);
        }
        for (; r < phi; r += 8) acc += ldrow(x, r, coff);
        *reinterpret_cast<f32x4*>(&s_part[rg][c4 * 4]) = acc;
        __syncthreads();

        const int par = k & 1;
        const size_t pbase = (((size_t)par * GSLOTS + gslot) * NPART) * NCH;
        if (tid < NCH) {
            float m = 0.f;
            #pragma unroll
            for (int i = 0; i < NPART; ++i) m += s_part[i][tid];
            part[pbase + (size_t)j * NCH + tid] = m;
        }
        __threadfence();
        __syncthreads();
        if (tid == 0)
            s_io = __hip_atomic_fetch_add(&cnt[g], 1, __ATOMIC_ACQ_REL, __HIP_MEMORY_SCOPE_AGENT);
        __syncthreads();

        if (s_io == NPART - 1) {
            // ---- this block finalizes graph g: reduce partials + MLP ----
            if (tid < NCH) {
                float m = 0.f;
                #pragma unroll
                for (int jj = 0; jj < NPART; ++jj) m += part[pbase + (size_t)jj * NCH + tid];
                m *= (len > 0) ? (1.0f / (float)len) : 1.0f;
                s_vec[tid] = m;
            }
            __syncthreads();
            if (tid < NCH) {
                const int jo = tid >> 4, sub = tid & 15;
                float hp = 0.f;
                #pragma unroll
                for (int i = 0; i < 16; ++i) { int c = sub * 16 + i; hp += s_vec[c] * W1[c * HID + jo]; }
                s_hp[jo][sub] = hp;
            }
            __syncthreads();
            if (tid < HID) {
                float h = 0.f;
                #pragma unroll
                for (int i = 0; i < 16; ++i) h += s_hp[tid][i];
                s_h[tid] = fmaxf(h, 0.f);
            }
            __syncthreads();
            if (tid < NCH) {
                float sc = 0.f;
                #pragma unroll
                for (int jj = 0; jj < HID; ++jj) sc += s_h[jj] * W2[jj * NCH + tid];
                scale[(size_t)g * NCH + tid] = 1.0f / (1.0f + __expf(-sc));
            }
            __threadfence();
            __syncthreads();
            if (tid == 0)
                __hip_atomic_store(&flg[g], 1, __ATOMIC_RELEASE, __HIP_MEMORY_SCOPE_AGENT);
        }

        // ---- write previous round's rows (mixed with this round's reads) ----
        if (k > 0)
            write_seg(x, out, scale, flg, pg, pplo, pphi, tid, rg, c4, coff);

        pg = g; pplo = plo; pphi = phi;
    }

    // ---- tail: write final round's rows ----
    write_seg(x, out, scale, flg, pg, pplo, pphi, tid, rg, c4, coff);
}

extern "C" void kernel_launch(void* const* d_in, const int* in_sizes, int n_in,
                              void* d_out, int out_size, void* d_ws, size_t ws_size,
                              hipStream_t stream) {
    const float* x     = (const float*)d_in[0];
    const int*   batch = (const int*)d_in[1];
    const float* W1    = (const float*)d_in[2];
    const float* W2    = (const float*)d_in[3];
    float*       out   = (float*)d_out;
    const int n = in_sizes[1];

    char* ws = (char*)d_ws;
    float* part  = (float*)ws;                               // 2*64*8*256*4 = 1 MiB
    float* scale = (float*)(ws + (1u << 20));                // 512*256*4   = 512 KiB
    int*   cnt   = (int*)(ws + (1u << 20) + (512u << 10));   // 2 KiB
    int*   flg   = (int*)(ws + (1u << 20) + (512u << 10) + 2048); // 2 KiB

    hipMemsetAsync(cnt, 0, 4096, stream);   // cnt + flg
    hipLaunchKernelGGL(graph_se_pipe, dim3(NGRAPH), dim3(512), 0, stream,
                       x, batch, W1, W2, out, part, scale, cnt, flg, n);
}

// Round 10
// 285.001 us; speedup vs baseline: 10.0209x; 10.0209x over previous
//
#include <hip/hip_runtime.h>

#define NCH 256
#define HID 16
#define NBLK 256   // each block handles graphs b and b+256

typedef __attribute__((ext_vector_type(4))) float f32x4;

// Non-temporal row load: bypass cache fill (testing the L3-fill-cap hypothesis)
__device__ __forceinline__ f32x4 ldrow(const float* __restrict__ x, int r, size_t coff) {
    return __builtin_nontemporal_load(reinterpret_cast<const f32x4*>(x + (size_t)r * NCH + coff));
}

__device__ __forceinline__ void strow(float* __restrict__ out, int r, size_t coff, f32x4 v) {
    __builtin_nontemporal_store(v, reinterpret_cast<f32x4*>(out + (size_t)r * NCH + coff));
}

__device__ __forceinline__ void se_mlp(const float* __restrict__ W1,
                                       const float* __restrict__ W2,
                                       float (&s_part)[16][NCH],
                                       int first, int npart, int cnt,
                                       float* __restrict__ s_vec,
                                       float (&s_hp)[HID][17], float (&s_h)[HID],
                                       int tid)
{
    if (tid < NCH) {
        float m = 0.f;
        for (int i = 0; i < npart; ++i) m += s_part[first + i][tid];
        m *= (cnt > 0) ? (1.0f / (float)cnt) : 1.0f;
        s_vec[tid] = m;
    }
    __syncthreads();
    if (tid < NCH) {
        const int j = tid >> 4, sub = tid & 15;
        float hp = 0.f;
        #pragma unroll
        for (int i = 0; i < 16; ++i) { int c = sub * 16 + i; hp += s_vec[c] * W1[c * HID + j]; }
        s_hp[j][sub] = hp;
    }
    __syncthreads();
    if (tid < HID) {
        float h = 0.f;
        #pragma unroll
        for (int i = 0; i < 16; ++i) h += s_hp[tid][i];
        s_h[tid] = fmaxf(h, 0.f);
    }
    __syncthreads();
    if (tid < NCH) {
        float sc = 0.f;
        #pragma unroll
        for (int j = 0; j < HID; ++j) sc += s_h[j] * W2[j * NCH + tid];
        s_vec[tid] = 1.0f / (1.0f + __expf(-sc));
    }
}

__global__ __launch_bounds__(1024, 4) void graph_se_kernel(
    const float* __restrict__ x,
    const int* __restrict__ batch,
    const float* __restrict__ W1,
    const float* __restrict__ W2,
    float* __restrict__ out,
    int n)
{
    const int b   = blockIdx.x;
    const int tid = threadIdx.x;

    __shared__ int   s_bnd[4];
    __shared__ float s_part[16][NCH];
    __shared__ float s_vecA[NCH];
    __shared__ float s_vecB[NCH];
    __shared__ float s_hp[HID][17];
    __shared__ float s_h[HID];

    // boundaries of graphs b, b+1, b+256, b+257 (batch sorted)
    if (tid < 4) {
        int v = (tid < 2) ? (b + tid) : (NBLK + b + (tid - 2));
        int lo = 0, hi = n;
        while (lo < hi) { int mid = (lo + hi) >> 1; if (batch[mid] < v) lo = mid + 1; else hi = mid; }
        s_bnd[tid] = lo;
    }
    __syncthreads();
    const int loA = s_bnd[0], hiA = s_bnd[1];
    const int loB = s_bnd[2], hiB = s_bnd[3];

    const int rg = tid >> 6;            // row group 0..15 (wave id)
    const int c4 = tid & 63;            // float4 lane within row
    const size_t coff = (size_t)c4 * 4;

    // ---- P1: pool A, 16 groups, 8 loads in flight ----
    {
        f32x4 acc = (f32x4)(0.f);
        int r = loA + rg;
        for (; r + 112 < hiA; r += 128) {
            f32x4 v0 = ldrow(x, r      , coff);
            f32x4 v1 = ldrow(x, r +  16, coff);
            f32x4 v2 = ldrow(x, r +  32, coff);
            f32x4 v3 = ldrow(x, r +  48, coff);
            f32x4 v4 = ldrow(x, r +  64, coff);
            f32x4 v5 = ldrow(x, r +  80, coff);
            f32x4 v6 = ldrow(x, r +  96, coff);
            f32x4 v7 = ldrow(x, r + 112, coff);
            acc += ((v0 + v1) + (v2 + v3)) + ((v4 + v5) + (v6 + v7));
        }
        for (; r < hiA; r += 16) acc += ldrow(x, r, coff);
        *reinterpret_cast<f32x4*>(&s_part[rg][c4 * 4]) = acc;
    }
    __syncthreads();

    // ---- MLP A -> s_vecA ----
    se_mlp(W1, W2, s_part, 0, 16, hiA - loA, s_vecA, s_hp, s_h, tid);
    __syncthreads();

    // ---- P3: waves 0-7 scale+write A  ||  waves 8-15 pool B ----
    if (rg < 8) {
        const f32x4 scv = *reinterpret_cast<const f32x4*>(&s_vecA[c4 * 4]);
        int r = loA + rg;
        for (; r + 24 < hiA; r += 32) {
            f32x4 v0 = ldrow(x, r     , coff);
            f32x4 v1 = ldrow(x, r +  8, coff);
            f32x4 v2 = ldrow(x, r + 16, coff);
            f32x4 v3 = ldrow(x, r + 24, coff);
            strow(out, r     , coff, v0 * scv);
            strow(out, r +  8, coff, v1 * scv);
            strow(out, r + 16, coff, v2 * scv);
            strow(out, r + 24, coff, v3 * scv);
        }
        for (; r < hiA; r += 8) {
            strow(out, r, coff, ldrow(x, r, coff) * scv);
        }
    } else {
        const int gid = rg - 8;
        f32x4 acc = (f32x4)(0.f);
        int r = loB + gid;
        for (; r + 56 < hiB; r += 64) {
            f32x4 v0 = ldrow(x, r     , coff);
            f32x4 v1 = ldrow(x, r +  8, coff);
            f32x4 v2 = ldrow(x, r + 16, coff);
            f32x4 v3 = ldrow(x, r + 24, coff);
            f32x4 v4 = ldrow(x, r + 32, coff);
            f32x4 v5 = ldrow(x, r + 40, coff);
            f32x4 v6 = ldrow(x, r + 48, coff);
            f32x4 v7 = ldrow(x, r + 56, coff);
            acc += ((v0 + v1) + (v2 + v3)) + ((v4 + v5) + (v6 + v7));
        }
        for (; r < hiB; r += 8) acc += ldrow(x, r, coff);
        *reinterpret_cast<f32x4*>(&s_part[rg][c4 * 4]) = acc;
    }
    __syncthreads();

    // ---- MLP B (partials 8..15) -> s_vecB ----
    se_mlp(W1, W2, s_part, 8, 8, hiB - loB, s_vecB, s_hp, s_h, tid);
    __syncthreads();

    // ---- P5: scale+write B, 16 groups ----
    {
        const f32x4 scv = *reinterpret_cast<const f32x4*>(&s_vecB[c4 * 4]);
        int r = loB + rg;
        for (; r + 48 < hiB; r += 64) {
            f32x4 v0 = ldrow(x, r     , coff);
            f32x4 v1 = ldrow(x, r + 16, coff);
            f32x4 v2 = ldrow(x, r + 32, coff);
            f32x4 v3 = ldrow(x, r + 48, coff);
            strow(out, r     , coff, v0 * scv);
            strow(out, r + 16, coff, v1 * scv);
            strow(out, r + 32, coff, v2 * scv);
            strow(out, r + 48, coff, v3 * scv);
        }
        for (; r < hiB; r += 16) {
            strow(out, r, coff, ldrow(x, r, coff) * scv);
        }
    }
}

extern "C" void kernel_launch(void* const* d_in, const int* in_sizes, int n_in,
                              void* d_out, int out_size, void* d_ws, size_t ws_size,
                              hipStream_t stream) {
    const float* x     = (const float*)d_in[0];
    const int*   batch = (const int*)d_in[1];
    const float* W1    = (const float*)d_in[2];
    const float* W2    = (const float*)d_in[3];
    float*       out   = (float*)d_out;
    const int n = in_sizes[1];

    hipLaunchKernelGGL(graph_se_kernel, dim3(NBLK), dim3(1024), 0, stream,
                       x, batch, W1, W2, out, n);
}

// Round 11
// 252.279 us; speedup vs baseline: 11.3206x; 1.1297x over previous
//
#include <hip/hip_runtime.h>

#define NCH 256
#define HID 16
#define NBLK 256       // each block: graphs b and b+256
#define SREG 16        // f32x4 reg-stash per thread
#define ALDS 128       // LDS-stashed rows of A
// A coverage: rows [loA, loA+256) regs (16 waves) + [loA+256, loA+384) LDS
// B coverage: rows [loB, loB+128) regs (8 pool waves)

typedef __attribute__((ext_vector_type(4))) float f32x4;

__device__ __forceinline__ f32x4 ldrow(const float* __restrict__ x, int r, size_t coff) {
    return *reinterpret_cast<const f32x4*>(x + (size_t)r * NCH + coff);
}

__device__ __forceinline__ void strow(float* __restrict__ out, int r, size_t coff, f32x4 v) {
    __builtin_nontemporal_store(v, reinterpret_cast<f32x4*>(out + (size_t)r * NCH + coff));
}

__device__ __forceinline__ void se_mlp(const float* __restrict__ W1,
                                       const float* __restrict__ W2,
                                       float (&s_part)[16][NCH],
                                       int first, int npart, int cnt,
                                       float* __restrict__ s_vec,
                                       float (&s_hp)[HID][17], float (&s_h)[HID],
                                       int tid)
{
    if (tid < NCH) {
        float m = 0.f;
        for (int i = 0; i < npart; ++i) m += s_part[first + i][tid];
        m *= (cnt > 0) ? (1.0f / (float)cnt) : 1.0f;
        s_vec[tid] = m;
    }
    __syncthreads();
    if (tid < NCH) {
        const int j = tid >> 4, sub = tid & 15;
        float hp = 0.f;
        #pragma unroll
        for (int i = 0; i < 16; ++i) { int c = sub * 16 + i; hp += s_vec[c] * W1[c * HID + j]; }
        s_hp[j][sub] = hp;
    }
    __syncthreads();
    if (tid < HID) {
        float h = 0.f;
        #pragma unroll
        for (int i = 0; i < 16; ++i) h += s_hp[tid][i];
        s_h[tid] = fmaxf(h, 0.f);
    }
    __syncthreads();
    if (tid < NCH) {
        float sc = 0.f;
        #pragma unroll
        for (int j = 0; j < HID; ++j) sc += s_h[j] * W2[j * NCH + tid];
        s_vec[tid] = 1.0f / (1.0f + __expf(-sc));
    }
}

__global__ __launch_bounds__(1024, 4) void graph_se_kernel(
    const float* __restrict__ x,
    const int* __restrict__ batch,
    const float* __restrict__ W1,
    const float* __restrict__ W2,
    float* __restrict__ out,
    int n)
{
    const int b   = blockIdx.x;
    const int tid = threadIdx.x;

    __shared__ float s_stash[ALDS][NCH];   // 128 KiB A-row stash
    __shared__ int   s_bnd[4];
    __shared__ float s_part[16][NCH];
    __shared__ float s_vecA[NCH];
    __shared__ float s_vecB[NCH];
    __shared__ float s_hp[HID][17];
    __shared__ float s_h[HID];

    if (tid < 4) {
        int v = (tid < 2) ? (b + tid) : (NBLK + b + (tid - 2));
        int lo = 0, hi = n;
        while (lo < hi) { int mid = (lo + hi) >> 1; if (batch[mid] < v) lo = mid + 1; else hi = mid; }
        s_bnd[tid] = lo;
    }
    __syncthreads();
    const int loA = s_bnd[0], hiA = s_bnd[1];
    const int loB = s_bnd[2], hiB = s_bnd[3];

    const int rg = tid >> 6;            // wave 0..15
    const int c4 = tid & 63;
    const size_t coff = (size_t)c4 * 4;

    f32x4 st[SREG];                     // static-indexed only (unrolled)

    // ---- P1: pool A; stash first 256 rows in regs, next 128 in LDS ----
    {
        f32x4 acc = (f32x4)(0.f);
        const int base = loA + rg;
        #pragma unroll
        for (int k = 0; k < SREG; ++k) {
            int rr = base + 16 * k;
            if (rr < hiA) { st[k] = ldrow(x, rr, coff); acc += st[k]; }
        }
        #pragma unroll
        for (int k = 0; k < 8; ++k) {
            int rr = base + 16 * (SREG + k);
            if (rr < hiA) {
                f32x4 v = ldrow(x, rr, coff);
                *reinterpret_cast<f32x4*>(&s_stash[rg + 16 * k][c4 * 4]) = v;
                acc += v;
            }
        }
        int r = loA + (16 * SREG + ALDS) + rg;
        for (; r + 48 < hiA; r += 64) {
            f32x4 v0 = ldrow(x, r     , coff);
            f32x4 v1 = ldrow(x, r + 16, coff);
            f32x4 v2 = ldrow(x, r + 32, coff);
            f32x4 v3 = ldrow(x, r + 48, coff);
            acc += (v0 + v1) + (v2 + v3);
        }
        for (; r < hiA; r += 16) acc += ldrow(x, r, coff);
        *reinterpret_cast<f32x4*>(&s_part[rg][c4 * 4]) = acc;
    }
    __syncthreads();

    se_mlp(W1, W2, s_part, 0, 16, hiA - loA, s_vecA, s_hp, s_h, tid);
    __syncthreads();

    // ---- P3: stash-writeback A; waves 0-7 finish A || waves 8-15 pool B ----
    {
        const f32x4 scvA = *reinterpret_cast<const f32x4*>(&s_vecA[c4 * 4]);
        // all waves: write reg-stashed A rows (no x read)
        #pragma unroll
        for (int k = 0; k < SREG; ++k) {
            int rr = loA + rg + 16 * k;
            if (rr < hiA) strow(out, rr, coff, st[k] * scvA);
        }
        if (rg < 8) {
            // LDS-stashed rows (no x read)
            #pragma unroll
            for (int j = 0; j < 16; ++j) {
                int i = rg + 8 * j;
                int rr = loA + 16 * SREG + i;
                if (rr < hiA) {
                    f32x4 v = *reinterpret_cast<const f32x4*>(&s_stash[i][c4 * 4]);
                    strow(out, rr, coff, v * scvA);
                }
            }
            // unstashed tail of A: read (L3) + scale + write
            int r = loA + (16 * SREG + ALDS) + rg;
            for (; r + 24 < hiA; r += 32) {
                f32x4 v0 = ldrow(x, r     , coff);
                f32x4 v1 = ldrow(x, r +  8, coff);
                f32x4 v2 = ldrow(x, r + 16, coff);
                f32x4 v3 = ldrow(x, r + 24, coff);
                strow(out, r     , coff, v0 * scvA);
                strow(out, r +  8, coff, v1 * scvA);
                strow(out, r + 16, coff, v2 * scvA);
                strow(out, r + 24, coff, v3 * scvA);
            }
            for (; r < hiA; r += 8) strow(out, r, coff, ldrow(x, r, coff) * scvA);
        } else {
            // pool B; stash first 128 rows in regs (st[] already flushed above)
            const int gid = rg - 8;
            f32x4 acc = (f32x4)(0.f);
            const int baseB = loB + gid;
            #pragma unroll
            for (int k = 0; k < SREG; ++k) {
                int rr = baseB + 8 * k;
                if (rr < hiB) { st[k] = ldrow(x, rr, coff); acc += st[k]; }
            }
            int r = baseB + 8 * SREG;
            for (; r + 24 < hiB; r += 32) {
                f32x4 v0 = ldrow(x, r     , coff);
                f32x4 v1 = ldrow(x, r +  8, coff);
                f32x4 v2 = ldrow(x, r + 16, coff);
                f32x4 v3 = ldrow(x, r + 24, coff);
                acc += (v0 + v1) + (v2 + v3);
            }
            for (; r < hiB; r += 8) acc += ldrow(x, r, coff);
            *reinterpret_cast<f32x4*>(&s_part[rg][c4 * 4]) = acc;
        }
    }
    __syncthreads();

    se_mlp(W1, W2, s_part, 8, 8, hiB - loB, s_vecB, s_hp, s_h, tid);
    __syncthreads();

    // ---- P5: write B (stash-writeback + unstashed rest) ----
    {
        const f32x4 scvB = *reinterpret_cast<const f32x4*>(&s_vecB[c4 * 4]);
        if (rg >= 8) {
            const int gid = rg - 8;
            #pragma unroll
            for (int k = 0; k < SREG; ++k) {
                int rr = loB + gid + 8 * k;
                if (rr < hiB) strow(out, rr, coff, st[k] * scvB);
            }
        }
        int r = loB + 8 * SREG + rg;
        for (; r + 48 < hiB; r += 64) {
            f32x4 v0 = ldrow(x, r     , coff);
            f32x4 v1 = ldrow(x, r + 16, coff);
            f32x4 v2 = ldrow(x, r + 32, coff);
            f32x4 v3 = ldrow(x, r + 48, coff);
            strow(out, r     , coff, v0 * scvB);
            strow(out, r + 16, coff, v1 * scvB);
            strow(out, r + 32, coff, v2 * scvB);
            strow(out, r + 48, coff, v3 * scvB);
        }
        for (; r < hiB; r += 16) strow(out, r, coff, ldrow(x, r, coff) * scvB);
    }
}

extern "C" void kernel_launch(void* const* d_in, const int* in_sizes, int n_in,
                              void* d_out, int out_size, void* d_ws, size_t ws_size,
                              hipStream_t stream) {
    const float* x     = (const float*)d_in[0];
    const int*   batch = (const int*)d_in[1];
    const float* W1    = (const float*)d_in[2];
    const float* W2    = (const float*)d_in[3];
    float*       out   = (float*)d_out;
    const int n = in_sizes[1];

    hipLaunchKernelGGL(graph_se_kernel, dim3(NBLK), dim3(1024), 0, stream,
                       x, batch, W1, W2, out, n);
}